// Round 6
// baseline (165.695 us; speedup 1.0000x reference)
//
#include <hip/hip_runtime.h>
#include <hip/hip_bf16.h>

#define IN_F 4096
#define OUT_F 11008
#define TOKENS 32
#define RANK 16
#define KSPLIT 16
#define KSLICE (IN_F / KSPLIT)     // 256
#define XP 264                     // u16 stride per LDS x-row (256 data + 8 pad)
#define OUT_ELEMS (TOKENS * OUT_F) // 352256

typedef unsigned short u16;
typedef __attribute__((ext_vector_type(8))) short bf16x8;
typedef __attribute__((ext_vector_type(16))) float f32x16;
typedef __attribute__((ext_vector_type(4))) int i32x4;

__device__ const float NF4_d[16] = {
    -1.0f, -0.6961928009986877f, -0.5250730514526367f, -0.39491748809814453f,
    -0.28444138169288635f, -0.18477343022823334f, -0.09105003625154495f, 0.0f,
    0.07958029955625534f, 0.16093020141124725f, 0.24611230194568634f,
    0.33791524171829224f, 0.44070982933044434f, 0.5626170039176941f,
    0.7229568362236023f, 1.0f};

static __device__ __forceinline__ unsigned pk2(float a, float b) {
    __hip_bfloat162 h = __float22bfloat162_rn(make_float2(a, b));
    unsigned u;
    __builtin_memcpy(&u, &h, 4);
    return u;
}

// kernel 1: blocks 0..511 compute xa[t][r] (shuffle-reduce); 512..575 zero out[]
__global__ void prep_xa_zero(const float* __restrict__ x, const float* __restrict__ A,
                             float* __restrict__ xa, float* __restrict__ out) {
    if (blockIdx.x >= 512) {
        int i = (blockIdx.x - 512) * 256 + threadIdx.x;  // 16384 threads
        float4 z = make_float4(0.f, 0.f, 0.f, 0.f);
        for (int j = i; j < OUT_ELEMS / 4; j += 16384) ((float4*)out)[j] = z;
        return;
    }
    int b = blockIdx.x;  // 0..511
    int t = b >> 4, r = b & 15;
    const float4* xr = (const float4*)(x + t * IN_F);
    const float4* ar = (const float4*)(A + r * IN_F);
    float s = 0.f;
    for (int c = 0; c < 4; ++c) {
        int j = c * 256 + threadIdx.x;
        float4 xv = xr[j], av = ar[j];
        s += xv.x * av.x + xv.y * av.y + xv.z * av.z + xv.w * av.w;
    }
    for (int off = 32; off > 0; off >>= 1) s += __shfl_down(s, off, 64);
    __shared__ float w4[4];
    if ((threadIdx.x & 63) == 0) w4[threadIdx.x >> 6] = s;
    __syncthreads();
    if (threadIdx.x == 0) xa[b] = w4[0] + w4[1] + w4[2] + w4[3];
}

// kernel 2: NF4 dequant (zero-VALU) + 32x32x16 MFMA + deferred scale + lora epilogue
__global__ __launch_bounds__(256, 4) void qlora_fused(
    const int* __restrict__ packed, const float* __restrict__ scales,
    const float* __restrict__ x, const float* __restrict__ xa,
    const float* __restrict__ B, float* __restrict__ out) {
    __shared__ u16 xs[32 * XP];    // 32 tokens x 256 k (bf16)
    __shared__ unsigned tbl[256];  // byte -> (bf16(lo)<<16)|bf16(hi): raw B-frag dword
    __shared__ float xal[512];     // xa staged (y==0 blocks)
    const int tid = threadIdx.x;
    const int lane = tid & 63;
    const int wv = tid >> 6;
    const int n = lane & 31;  // output col within wave tile (and token row for A)
    const int h = lane >> 5;  // k-half selector
    const int kbase = blockIdx.y * KSLICE;
    const int o = blockIdx.x * 128 + wv * 32 + n;

    // deep nontemporal prefetch of the packed stream (90 MB single-use)
    // step s: MFMA0 bytes at int32 ofs s*16 + h*4, MFMA1 at s*16 + 8 + h*4
    const i32x4* ppq = (const i32x4*)(packed + o * 2048 + (kbase >> 1) + h * 4);
    i32x4 Pa[2], Pb[2];
    Pa[0] = __builtin_nontemporal_load(ppq + 0);
    Pb[0] = __builtin_nontemporal_load(ppq + 2);
    Pa[1] = __builtin_nontemporal_load(ppq + 4);
    Pb[1] = __builtin_nontemporal_load(ppq + 6);

    // per-lane group scales: 4 groups per 256-k slice, column o fixed per lane
    float4 sv = *(const float4*)(scales + o * 64 + (kbase >> 6));
    const float scr[4] = {sv.x, sv.y, sv.z, sv.w};

    // swapped table: low16 = bf16(hi-nibble code) (k even), high16 = bf16(lo code)
    tbl[tid] = pk2(NF4_d[tid >> 4], NF4_d[tid & 15]);

    if (blockIdx.y == 0) {  // stage xa for lora epilogue
        xal[tid] = xa[tid];
        xal[tid + 256] = xa[tid + 256];
    }

    // stage x slice: 32 rows x 256 cols, fp32 -> bf16 (8 threads/row, 32 elems each)
    {
        int row = tid >> 3;
        int c = (tid & 7) * 32;
        const float4* src = (const float4*)(x + row * IN_F + kbase + c);
        u16* dst = xs + row * XP + c;
#pragma unroll
        for (int j = 0; j < 4; ++j) {
            float4 a = src[j * 2], b2 = src[j * 2 + 1];
            uint4 d;
            d.x = pk2(a.x, a.y);
            d.y = pk2(a.z, a.w);
            d.z = pk2(b2.x, b2.y);
            d.w = pk2(b2.z, b2.w);
            *(uint4*)(dst + j * 8) = d;
        }
    }
    __syncthreads();

    f32x16 acc = {};
    f32x16 sub;
    const f32x16 Z = {};
    // A-frag: token m = lane&31, k = h*8 + j (within each MFMA's k-16 half)
    const u16* ar = xs + (lane & 31) * XP + h * 8;

#pragma unroll
    for (int s = 0; s < 8; ++s) {
        i32x4 ca = Pa[s & 1], cb = Pb[s & 1];
        if (s + 2 < 8) {
            Pa[s & 1] = __builtin_nontemporal_load(ppq + (s + 2) * 4);
            Pb[s & 1] = __builtin_nontemporal_load(ppq + (s + 2) * 4 + 2);
        }
        uint4 b0u, b1u;
        b0u.x = tbl[ca[0] & 255];
        b0u.y = tbl[ca[1] & 255];
        b0u.z = tbl[ca[2] & 255];
        b0u.w = tbl[ca[3] & 255];
        b1u.x = tbl[cb[0] & 255];
        b1u.y = tbl[cb[1] & 255];
        b1u.z = tbl[cb[2] & 255];
        b1u.w = tbl[cb[3] & 255];
        bf16x8 bf0, bf1;
        __builtin_memcpy(&bf0, &b0u, 16);
        __builtin_memcpy(&bf1, &b1u, 16);
        bf16x8 a0 = *(const bf16x8*)(ar + s * 32);
        bf16x8 a1 = *(const bf16x8*)(ar + s * 32 + 16);
        if ((s & 1) == 0) {
            sub = __builtin_amdgcn_mfma_f32_32x32x16_bf16(a0, bf0, Z, 0, 0, 0);
            sub = __builtin_amdgcn_mfma_f32_32x32x16_bf16(a1, bf1, sub, 0, 0, 0);
        } else {
            sub = __builtin_amdgcn_mfma_f32_32x32x16_bf16(a0, bf0, sub, 0, 0, 0);
            sub = __builtin_amdgcn_mfma_f32_32x32x16_bf16(a1, bf1, sub, 0, 0, 0);
            float sc = scr[s >> 1];  // one 64-k group spans 2 steps
#pragma unroll
            for (int i = 0; i < 16; ++i) acc[i] += sc * sub[i];
        }
    }

    // C layout (32x32): col = lane&31 (= o), row/token t = (i&3) + 8*(i>>2) + 4*h
    if (blockIdx.y == 0) {
        const float4* br = (const float4*)(B + o * RANK);
        float4 b0 = br[0], b1 = br[1], b2 = br[2], b3 = br[3];
#pragma unroll
        for (int i = 0; i < 16; ++i) {
            int t = (i & 3) + 8 * (i >> 2) + 4 * h;
            const float4* xt = (const float4*)(xal + t * RANK);
            float4 x0 = xt[0], x1 = xt[1], x2 = xt[2], x3 = xt[3];
            float lor = b0.x * x0.x + b0.y * x0.y + b0.z * x0.z + b0.w * x0.w +
                        b1.x * x1.x + b1.y * x1.y + b1.z * x1.z + b1.w * x1.w +
                        b2.x * x2.x + b2.y * x2.y + b2.z * x2.z + b2.w * x2.w +
                        b3.x * x3.x + b3.y * x3.y + b3.z * x3.z + b3.w * x3.w;
            atomicAdd(out + t * OUT_F + o, acc[i] + lor);
        }
    } else {
#pragma unroll
        for (int i = 0; i < 16; ++i) {
            int t = (i & 3) + 8 * (i >> 2) + 4 * h;
            atomicAdd(out + t * OUT_F + o, acc[i]);
        }
    }
}

extern "C" void kernel_launch(void* const* d_in, const int* in_sizes, int n_in,
                              void* d_out, int out_size, void* d_ws, size_t ws_size,
                              hipStream_t stream) {
    const float* x = (const float*)d_in[0];
    const int* packed = (const int*)d_in[1];
    const float* scales = (const float*)d_in[2];
    const float* lora_A = (const float*)d_in[3];
    const float* lora_B = (const float*)d_in[4];
    float* out = (float*)d_out;

    float* xa = (float*)d_ws;  // 2048 B

    prep_xa_zero<<<576, 256, 0, stream>>>(x, lora_A, xa, out);
    qlora_fused<<<dim3(OUT_F / 128, KSPLIT), 256, 0, stream>>>(packed, scales, x, xa,
                                                               lora_B, out);
}

// Round 7
// 152.769 us; speedup vs baseline: 1.0846x; 1.0846x over previous
//
#include <hip/hip_runtime.h>
#include <hip/hip_bf16.h>

#define IN_F 4096
#define OUT_F 11008
#define TOKENS 32
#define RANK 16
#define KSPLIT 8
#define KSLICE (IN_F / KSPLIT)  // 512
#define XPAD 520                // u16 per LDS x-row (512 data + 8 pad)
#define OUT_ELEMS (TOKENS * OUT_F)  // 352256

typedef unsigned short u16;
typedef __attribute__((ext_vector_type(8))) short bf16x8;
typedef __attribute__((ext_vector_type(4))) float f32x4;
typedef __attribute__((ext_vector_type(4))) int i32x4;

__device__ const float NF4_d[16] = {
    -1.0f, -0.6961928009986877f, -0.5250730514526367f, -0.39491748809814453f,
    -0.28444138169288635f, -0.18477343022823334f, -0.09105003625154495f, 0.0f,
    0.07958029955625534f, 0.16093020141124725f, 0.24611230194568634f,
    0.33791524171829224f, 0.44070982933044434f, 0.5626170039176941f,
    0.7229568362236023f, 1.0f};

static __device__ __forceinline__ unsigned pk2(float a, float b) {
    __hip_bfloat162 h = __float22bfloat162_rn(make_float2(a, b));
    unsigned u;
    __builtin_memcpy(&u, &h, 4);
    return u;
}

// kernel 1: blocks 0..511 compute xa[t][r]; blocks 512..575 zero out[]
__global__ void prep_xa_zero(const float* __restrict__ x, const float* __restrict__ A,
                             float* __restrict__ xa, float* __restrict__ out) {
    __shared__ float red[256];
    if (blockIdx.x >= 512) {
        int i = (blockIdx.x - 512) * 256 + threadIdx.x;  // 16384 threads
        float4 z = make_float4(0.f, 0.f, 0.f, 0.f);
        for (int j = i; j < OUT_ELEMS / 4; j += 16384) ((float4*)out)[j] = z;
        return;
    }
    int b = blockIdx.x;  // 0..511
    int t = b >> 4, r = b & 15;
    const float4* xr = (const float4*)(x + t * IN_F);
    const float4* ar = (const float4*)(A + r * IN_F);
    float s = 0.f;
    for (int c = 0; c < 4; ++c) {
        int j = c * 256 + threadIdx.x;
        float4 xv = xr[j], av = ar[j];
        s += xv.x * av.x + xv.y * av.y + xv.z * av.z + xv.w * av.w;
    }
    red[threadIdx.x] = s;
    __syncthreads();
    for (int st = 128; st > 0; st >>= 1) {
        if (threadIdx.x < st) red[threadIdx.x] += red[threadIdx.x + st];
        __syncthreads();
    }
    if (threadIdx.x == 0) xa[b] = red[0];
}

// kernel 2: NF4 dequant + bf16 MFMA; 128-output blocks, 4 acc chains/wave
__global__ __launch_bounds__(256, 4) void qlora_fused(
    const int* __restrict__ packed, const float* __restrict__ scales,
    const float* __restrict__ x, const float* __restrict__ xa,
    const float* __restrict__ B, float* __restrict__ out) {
    __shared__ u16 xs[32 * XPAD];  // 32 tokens x 512 k (bf16), padded rows
    __shared__ unsigned tbl[256];  // byte -> packed bf16 (hi16=hi, lo16=lo)
    __shared__ float xal[512];     // xa staged (y==0 blocks)
    const int tid = threadIdx.x;
    const int kbase = blockIdx.y * KSLICE;

    const int lane = tid & 63;
    const int wv = tid >> 6;
    const int n = lane & 15;  // output col within 16-group / token row for A
    const int q = lane >> 4;  // k-subblock
    const int olo = blockIdx.x * 128 + wv * 32 + n;
    const int ohi = olo + 16;

    // two nontemporal packed streams (rows olo, ohi), prefetch depth 2 each
    const i32x4* pp0 = (const i32x4*)(packed + olo * 2048 + (kbase >> 1)) + q;
    const i32x4* pp1 = (const i32x4*)(packed + ohi * 2048 + (kbase >> 1)) + q;
    i32x4 P0[2], P1[2];
    P0[0] = __builtin_nontemporal_load(pp0);
    P1[0] = __builtin_nontemporal_load(pp1);
    P0[1] = __builtin_nontemporal_load(pp0 + 4);
    P1[1] = __builtin_nontemporal_load(pp1 + 4);

    // per-lane group scales for both output rows (8 floats each, contiguous)
    const float4* sp0 = (const float4*)(scales + olo * 64 + (kbase >> 6));
    const float4* sp1 = (const float4*)(scales + ohi * 64 + (kbase >> 6));
    float4 s0A = sp0[0], s0B = sp0[1];
    float4 s1A = sp1[0], s1B = sp1[1];

    // dequant table: hi16 = bf16(hi-nibble code), lo16 = bf16(lo-nibble code)
    tbl[tid] = pk2(NF4_d[tid & 15], NF4_d[tid >> 4]);

    if (blockIdx.y == 0) {  // stage xa for lora epilogue
        xal[tid] = xa[tid];
        xal[tid + 256] = xa[tid + 256];
    }

    // stage x slice: 32 rows x 512, fp32 -> bf16 during staging
    for (int it = 0; it < 8; ++it) {
        int row = it * 4 + (tid >> 6);
        int c8 = tid & 63;
        const float4* src = (const float4*)(x + row * IN_F + kbase + c8 * 8);
        float4 v0 = src[0], v1 = src[1];
        uint4 d;
        d.x = pk2(v0.x, v0.y);
        d.y = pk2(v0.z, v0.w);
        d.z = pk2(v1.x, v1.y);
        d.w = pk2(v1.z, v1.w);
        *(uint4*)(xs + row * XPAD + c8 * 8) = d;
    }
    __syncthreads();

    f32x4 acc00 = {0.f, 0.f, 0.f, 0.f};  // tokens 0-15  x outs lo
    f32x4 acc10 = {0.f, 0.f, 0.f, 0.f};  // tokens 16-31 x outs lo
    f32x4 acc01 = {0.f, 0.f, 0.f, 0.f};  // tokens 0-15  x outs hi
    f32x4 acc11 = {0.f, 0.f, 0.f, 0.f};  // tokens 16-31 x outs hi
    const u16* xr0 = xs + n * XPAD + q * 8;
    const u16* xr1 = xs + (n + 16) * XPAD + q * 8;
    const float sc0r[8] = {s0A.x, s0A.y, s0A.z, s0A.w, s0B.x, s0B.y, s0B.z, s0B.w};
    const float sc1r[8] = {s1A.x, s1A.y, s1A.z, s1A.w, s1B.x, s1B.y, s1B.z, s1B.w};

#pragma unroll
    for (int s = 0; s < 16; ++s) {
        i32x4 c0 = P0[s & 1];
        i32x4 c1 = P1[s & 1];
        if (s + 2 < 16) {
            P0[s & 1] = __builtin_nontemporal_load(pp0 + (s + 2) * 4);
            P1[s & 1] = __builtin_nontemporal_load(pp1 + (s + 2) * 4);
        }
        float sc0 = sc0r[s >> 1];  // compile-time select (fully unrolled)
        float sc1 = sc1r[s >> 1];

        uint4 b0u, b1u;
        {
            unsigned u0 = tbl[c0[0] & 255], u1 = tbl[c0[1] & 255];
            unsigned u2 = tbl[c0[2] & 255], u3 = tbl[c0[3] & 255];
            b0u.x = pk2(__int_as_float(u0 & 0xFFFF0000u) * sc0, __int_as_float(u0 << 16) * sc0);
            b0u.y = pk2(__int_as_float(u1 & 0xFFFF0000u) * sc0, __int_as_float(u1 << 16) * sc0);
            b0u.z = pk2(__int_as_float(u2 & 0xFFFF0000u) * sc0, __int_as_float(u2 << 16) * sc0);
            b0u.w = pk2(__int_as_float(u3 & 0xFFFF0000u) * sc0, __int_as_float(u3 << 16) * sc0);
        }
        {
            unsigned u0 = tbl[c1[0] & 255], u1 = tbl[c1[1] & 255];
            unsigned u2 = tbl[c1[2] & 255], u3 = tbl[c1[3] & 255];
            b1u.x = pk2(__int_as_float(u0 & 0xFFFF0000u) * sc1, __int_as_float(u0 << 16) * sc1);
            b1u.y = pk2(__int_as_float(u1 & 0xFFFF0000u) * sc1, __int_as_float(u1 << 16) * sc1);
            b1u.z = pk2(__int_as_float(u2 & 0xFFFF0000u) * sc1, __int_as_float(u2 << 16) * sc1);
            b1u.w = pk2(__int_as_float(u3 & 0xFFFF0000u) * sc1, __int_as_float(u3 << 16) * sc1);
        }
        bf16x8 bf0, bf1;
        __builtin_memcpy(&bf0, &b0u, 16);
        __builtin_memcpy(&bf1, &b1u, 16);
        bf16x8 a0 = *(const bf16x8*)(xr0 + s * 32);
        bf16x8 a1 = *(const bf16x8*)(xr1 + s * 32);
        acc00 = __builtin_amdgcn_mfma_f32_16x16x32_bf16(a0, bf0, acc00, 0, 0, 0);
        acc10 = __builtin_amdgcn_mfma_f32_16x16x32_bf16(a1, bf0, acc10, 0, 0, 0);
        acc01 = __builtin_amdgcn_mfma_f32_16x16x32_bf16(a0, bf1, acc01, 0, 0, 0);
        acc11 = __builtin_amdgcn_mfma_f32_16x16x32_bf16(a1, bf1, acc11, 0, 0, 0);
    }

    // C/D layout: col = lane&15 (o), row = q*4 + reg (token)
    if (blockIdx.y == 0) {
        const float4* brl = (const float4*)(B + olo * RANK);
        const float4* brh = (const float4*)(B + ohi * RANK);
        float4 l0 = brl[0], l1 = brl[1], l2 = brl[2], l3 = brl[3];
        float4 h0 = brh[0], h1 = brh[1], h2 = brh[2], h3 = brh[3];
#pragma unroll
        for (int r = 0; r < 4; ++r) {
            int t = q * 4 + r;
#pragma unroll
            for (int half = 0; half < 2; ++half) {
                int tt = t + half * 16;
                const float4* xt = (const float4*)(xal + tt * RANK);
                float4 x0 = xt[0], x1 = xt[1], x2 = xt[2], x3 = xt[3];
                float lorL = l0.x * x0.x + l0.y * x0.y + l0.z * x0.z + l0.w * x0.w +
                             l1.x * x1.x + l1.y * x1.y + l1.z * x1.z + l1.w * x1.w +
                             l2.x * x2.x + l2.y * x2.y + l2.z * x2.z + l2.w * x2.w +
                             l3.x * x3.x + l3.y * x3.y + l3.z * x3.z + l3.w * x3.w;
                float lorH = h0.x * x0.x + h0.y * x0.y + h0.z * x0.z + h0.w * x0.w +
                             h1.x * x1.x + h1.y * x1.y + h1.z * x1.z + h1.w * x1.w +
                             h2.x * x2.x + h2.y * x2.y + h2.z * x2.z + h2.w * x2.w +
                             h3.x * x3.x + h3.y * x3.y + h3.z * x3.z + h3.w * x3.w;
                float aL = half ? acc10[r] : acc00[r];
                float aH = half ? acc11[r] : acc01[r];
                atomicAdd(out + tt * OUT_F + olo, aL + lorL);
                atomicAdd(out + tt * OUT_F + ohi, aH + lorH);
            }
        }
    } else {
#pragma unroll
        for (int r = 0; r < 4; ++r) {
            int t = q * 4 + r;
            atomicAdd(out + t * OUT_F + olo, acc00[r]);
            atomicAdd(out + (t + 16) * OUT_F + olo, acc10[r]);
            atomicAdd(out + t * OUT_F + ohi, acc01[r]);
            atomicAdd(out + (t + 16) * OUT_F + ohi, acc11[r]);
        }
    }
}

extern "C" void kernel_launch(void* const* d_in, const int* in_sizes, int n_in,
                              void* d_out, int out_size, void* d_ws, size_t ws_size,
                              hipStream_t stream) {
    const float* x = (const float*)d_in[0];
    const int* packed = (const int*)d_in[1];
    const float* scales = (const float*)d_in[2];
    const float* lora_A = (const float*)d_in[3];
    const float* lora_B = (const float*)d_in[4];
    float* out = (float*)d_out;

    float* xa = (float*)d_ws;  // 2048 B

    prep_xa_zero<<<576, 256, 0, stream>>>(x, lora_A, xa, out);
    qlora_fused<<<dim3(OUT_F / 128, KSPLIT), 256, 0, stream>>>(packed, scales, x, xa,
                                                               lora_B, out);
}